// Round 1
// baseline (1043.035 us; speedup 1.0000x reference)
//
#include <hip/hip_runtime.h>

// Bag-level attention selector.
//   repre:        (200000, 690) fp32
//   relation_mat: (53, 690) fp32
//   bias:         (53,) fp32
//   scope:        (25000, 2) int  (contiguous [start,end) per bag)
//   labels:       (200000,) int
//   out:          (25000, 53) fp32
//
// Strategy: one block handles G=8 bags. Per bag: per-instance logits
// (wave-per-row dot with relation_mat[label]) -> block softmax -> weighted
// row-sum att[g] in LDS. Then one joint pass computes att @ relation_mat.T
// for all 8 bags, loading each relation row once per block (8x amortized).
// repre is read from HBM once (phase-B re-read hits L2: bag rows were just
// touched in phase A).

#define NBAGS_TOT 25000
#define DDIM      690
#define D2        345     // DDIM/2 (float2 elements per row; rows are 8B-aligned)
#define RREL      53
#define G_BAGS    8
#define MAXBAG    1024    // max instances per bag (true max ~100 for this seed)
#define BLOCK     256

__global__ __launch_bounds__(BLOCK) void bag_attn_kernel(
    const float* __restrict__ repre,
    const float* __restrict__ rel,
    const float* __restrict__ bias,
    const int*   __restrict__ scope,
    const int*   __restrict__ labels,
    float*       __restrict__ out)
{
    __shared__ float s_w[MAXBAG];          // per-bag logits -> weights (4 KB)
    __shared__ float s_att[G_BAGS * DDIM]; // 8 att vectors (22 KB)
    __shared__ float s_red[8];             // block-reduction scratch

    const int tid  = threadIdx.x;
    const int lane = tid & 63;
    const int wave = tid >> 6;
    const int bag0 = blockIdx.x * G_BAGS;

    const float2* rel2 = (const float2*)rel;

    for (int g = 0; g < G_BAGS; ++g) {
        const int bag   = bag0 + g;
        const int start = scope[2 * bag];
        const int end   = scope[2 * bag + 1];
        int size = end - start;
        if (size > MAXBAG) size = MAXBAG;

        // ---- Phase A: rel_logits[j] = dot(repre[start+j], rel[labels[start+j]])
        for (int j = wave; j < size; j += 4) {
            const int row = start + j;
            const float2* rp = (const float2*)(repre + (size_t)row * DDIM);
            const float2* rl = rel2 + (size_t)labels[row] * D2;
            float acc = 0.f;
            #pragma unroll
            for (int k = 0; k < 6; ++k) {
                int f = lane + 64 * k;
                if (f < D2) {
                    float2 v = rp[f];
                    float2 u = rl[f];
                    acc = fmaf(v.x, u.x, fmaf(v.y, u.y, acc));
                }
            }
            #pragma unroll
            for (int o = 32; o; o >>= 1) acc += __shfl_xor(acc, o, 64);
            if (lane == 0) s_w[j] = acc;
        }
        __syncthreads();

        // ---- Softmax over s_w[0..size)
        float lm = -3.402823466e38f;
        for (int j = tid; j < size; j += BLOCK) lm = fmaxf(lm, s_w[j]);
        #pragma unroll
        for (int o = 32; o; o >>= 1) lm = fmaxf(lm, __shfl_xor(lm, o, 64));
        if (lane == 0) s_red[wave] = lm;
        __syncthreads();
        const float m = fmaxf(fmaxf(s_red[0], s_red[1]),
                              fmaxf(s_red[2], s_red[3]));
        __syncthreads();   // s_red reuse below

        float ls = 0.f;
        for (int j = tid; j < size; j += BLOCK) {
            float e = expf(s_w[j] - m);
            s_w[j] = e;    // each j owned by exactly one thread
            ls += e;
        }
        #pragma unroll
        for (int o = 32; o; o >>= 1) ls += __shfl_xor(ls, o, 64);
        if (lane == 0) s_red[wave] = ls;
        __syncthreads();
        const float inv = 1.f / (s_red[0] + s_red[1] + s_red[2] + s_red[3]);
        for (int j = tid; j < size; j += BLOCK) s_w[j] *= inv;
        __syncthreads();

        // ---- Phase B: att[g] = sum_j w[j] * repre[start+j]  (rows hot in L2)
        float2* att2 = (float2*)(s_att + g * DDIM);
        for (int f = tid; f < D2; f += BLOCK) {
            float ax = 0.f, ay = 0.f;
            const float2* rp = (const float2*)(repre + (size_t)start * DDIM) + f;
            for (int j = 0; j < size; ++j) {
                const float w  = s_w[j];
                const float2 v = rp[(size_t)j * D2];
                ax = fmaf(w, v.x, ax);
                ay = fmaf(w, v.y, ay);
            }
            att2[f] = make_float2(ax, ay);
        }
        __syncthreads();   // s_w / s_red reuse next bag; att complete
    }

    // ---- Phase C: out[bag0+g, r] = dot(att[g], rel[r]) + bias[r]
    // Each wave loads a rel row once, dots it with all 8 att vectors.
    for (int r = wave; r < RREL; r += 4) {
        const float2* rl = rel2 + (size_t)r * D2;
        float acc[G_BAGS];
        #pragma unroll
        for (int g = 0; g < G_BAGS; ++g) acc[g] = 0.f;
        #pragma unroll
        for (int k = 0; k < 6; ++k) {
            int f = lane + 64 * k;
            if (f < D2) {
                float2 u = rl[f];
                #pragma unroll
                for (int g = 0; g < G_BAGS; ++g) {
                    const float2* a2 = (const float2*)(s_att + g * DDIM);
                    float2 a = a2[f];
                    acc[g] = fmaf(u.x, a.x, fmaf(u.y, a.y, acc[g]));
                }
            }
        }
        const float b = bias[r];
        #pragma unroll
        for (int g = 0; g < G_BAGS; ++g) {
            float v = acc[g];
            #pragma unroll
            for (int o = 32; o; o >>= 1) v += __shfl_xor(v, o, 64);
            if (lane == 0) out[(size_t)(bag0 + g) * RREL + r] = v + b;
        }
    }
}

extern "C" void kernel_launch(void* const* d_in, const int* in_sizes, int n_in,
                              void* d_out, int out_size, void* d_ws, size_t ws_size,
                              hipStream_t stream)
{
    const float* repre  = (const float*)d_in[0];
    const float* rel    = (const float*)d_in[1];
    const float* bias   = (const float*)d_in[2];
    const int*   scope  = (const int*)d_in[3];
    const int*   labels = (const int*)d_in[4];
    float*       out    = (float*)d_out;

    const int grid = NBAGS_TOT / G_BAGS;  // 3125, exact
    bag_attn_kernel<<<grid, BLOCK, 0, stream>>>(repre, rel, bias, scope, labels, out);
}

// Round 2
// 994.497 us; speedup vs baseline: 1.0488x; 1.0488x over previous
//
#include <hip/hip_runtime.h>

// Bag-level attention selector — wave-per-bag, single-pass online softmax.
//   repre:        (200000, 690) fp32   <- 552 MB, dominant HBM traffic
//   relation_mat: (53, 690) fp32
//   bias:         (53,) fp32
//   scope:        (25000, 2) int       (contiguous [start,end) per bag)
//   labels:       (200000,) int
//   out:          (25000, 53) fp32
//
// One wave handles one bag: each row is loaded ONCE (lane-strided float2,
// coalesced), used for both the label-dot and the online-softmax-rescaled
// accumulator. No barriers in the main loop. 8 waves/block = 8 bags; one
// __syncthreads(), then joint phase C: each rel row loaded once per block,
// dotted against all 8 att vectors in LDS (8x amortization of rel traffic).

#define NBAGS  25000
#define DDIM   690
#define D2     345      // float2 elements per row (rows are 8B-aligned)
#define RREL   53
#define WAVES  8
#define BLOCK  512      // 8 waves

__global__ __launch_bounds__(BLOCK, 4) void bag_attn_kernel(
    const float* __restrict__ repre,
    const float* __restrict__ rel,
    const float* __restrict__ bias,
    const int*   __restrict__ scope,
    const int*   __restrict__ labels,
    float*       __restrict__ out)
{
    __shared__ float s_att[WAVES * DDIM];   // 22 KB: 8 normalized att vectors

    const int tid  = threadIdx.x;
    const int lane = tid & 63;
    const int wave = tid >> 6;
    const int bag  = blockIdx.x * WAVES + wave;

    const int start = scope[2 * bag];
    const int end   = scope[2 * bag + 1];

    const float2* rel2 = (const float2*)rel;

    // Online-softmax state + lane-strided accumulator (f = lane + 64k, k<6)
    float2 acc[6];
    #pragma unroll
    for (int k = 0; k < 6; ++k) acc[k] = make_float2(0.f, 0.f);
    float m = -3.402823466e38f;
    float l = 0.f;

    for (int row = start; row < end; ++row) {
        const float2* rp = (const float2*)(repre + (size_t)row * DDIM);
        const float2* rl = rel2 + (size_t)labels[row] * D2;

        float2 v[6];
        float dot = 0.f;
        #pragma unroll
        for (int k = 0; k < 6; ++k) {
            const int f = lane + 64 * k;
            if (f < D2) {
                v[k] = rp[f];
                const float2 u = rl[f];
                dot = fmaf(v[k].x, u.x, fmaf(v[k].y, u.y, dot));
            } else {
                v[k] = make_float2(0.f, 0.f);
            }
        }
        #pragma unroll
        for (int o = 32; o; o >>= 1) dot += __shfl_xor(dot, o, 64);

        const float nm = fmaxf(m, dot);
        const float sc = __expf(m - nm);    // first iter: exp(-inf)=0
        const float e  = __expf(dot - nm);
        l = fmaf(l, sc, e);
        #pragma unroll
        for (int k = 0; k < 6; ++k) {
            acc[k].x = fmaf(acc[k].x, sc, e * v[k].x);
            acc[k].y = fmaf(acc[k].y, sc, e * v[k].y);
        }
        m = nm;
    }

    // Normalize and publish att vector to LDS
    const float inv = 1.f / l;
    float2* satt2 = (float2*)(s_att + wave * DDIM);
    #pragma unroll
    for (int k = 0; k < 6; ++k) {
        const int f = lane + 64 * k;
        if (f < D2) satt2[f] = make_float2(acc[k].x * inv, acc[k].y * inv);
    }
    __syncthreads();

    // Phase C: out[bag0+g, r] = dot(att[g], rel[r]) + bias[r]
    // Each rel row loaded once per block, dotted against all 8 att vectors.
    const int bag0 = blockIdx.x * WAVES;
    for (int r = wave; r < RREL; r += WAVES) {
        const float2* rl = rel2 + (size_t)r * D2;
        float2 u[6];
        #pragma unroll
        for (int k = 0; k < 6; ++k) {
            const int f = lane + 64 * k;
            u[k] = (f < D2) ? rl[f] : make_float2(0.f, 0.f);
        }
        const float b = bias[r];
        #pragma unroll
        for (int g = 0; g < WAVES; ++g) {
            const float2* a2 = (const float2*)(s_att + g * DDIM);
            float dot = 0.f;
            #pragma unroll
            for (int k = 0; k < 6; ++k) {
                const int f = lane + 64 * k;
                if (f < D2) {
                    const float2 a = a2[f];
                    dot = fmaf(u[k].x, a.x, fmaf(u[k].y, a.y, dot));
                }
            }
            #pragma unroll
            for (int o = 32; o; o >>= 1) dot += __shfl_xor(dot, o, 64);
            if (lane == 0) out[(size_t)(bag0 + g) * RREL + r] = dot + b;
        }
    }
}

extern "C" void kernel_launch(void* const* d_in, const int* in_sizes, int n_in,
                              void* d_out, int out_size, void* d_ws, size_t ws_size,
                              hipStream_t stream)
{
    const float* repre  = (const float*)d_in[0];
    const float* rel    = (const float*)d_in[1];
    const float* bias   = (const float*)d_in[2];
    const int*   scope  = (const int*)d_in[3];
    const int*   labels = (const int*)d_in[4];
    float*       out    = (float*)d_out;

    const int grid = NBAGS / WAVES;   // 3125, exact
    bag_attn_kernel<<<grid, BLOCK, 0, stream>>>(repre, rel, bias, scope, labels, out);
}